// Round 8
// baseline (350.645 us; speedup 1.0000x reference)
//
#include <hip/hip_runtime.h>

#define Himg 135
#define Wimg 240
#define Bimg 128
#define Cimg 3
#define BCN (Bimg*Cimg)
#define HW (Himg*Wimg)
#define CHW (Cimg*HW)
#define TOTAL (BCN*HW)
#define EPSF 1e-10f

typedef float fvec4 __attribute__((ext_vector_type(4)));
typedef _Float16 hf;
typedef hf h8 __attribute__((ext_vector_type(8)));
typedef hf h4 __attribute__((ext_vector_type(4)));
typedef float f4 __attribute__((ext_vector_type(4)));

// Compile-time exp (double Taylor) — weights within 1 ulp of reference fp32.
constexpr double cexp(double x) {
  double s = 1.0, t = 1.0;
  for (int i = 1; i < 48; ++i) { t *= x / (double)i; s += t; }
  return s;
}
template<int N>
struct GaussW {
  float w[N];
  constexpr GaussW() : w{} {
    const float sig = (float)N / 5.0f;
    const float inv = 1.0f / (2.0f * sig * sig);
    float ws[N] = {};
    float ssum = 0.f;
    for (int i = 0; i < N; ++i) {
      float d = (float)(i - N / 2);
      ws[i] = (float)cexp((double)(-(d * d) * inv));
      ssum += ws[i];
    }
    for (int i = 0; i < N; ++i) w[i] = ws[i] / ssum;
  }
};

// ws layout (floats): [0,384) num, [384,768) den, [768,896) per-image dots

// LDS (half units): Ar [80][40], Ap [80][40], H [80][84] (5ch x 16col + pad)
#define SR 40
#define SH 84
#define AOFF (80*SR)
#define HOFF (2*80*SR)
#define LDSB ((2*80*SR + 80*SH)*2)

template<int N>
__device__ __forceinline__ void vif_body(
    int b, const float* __restrict__ recons, const float* __restrict__ xim,
    float* __restrict__ numg, float* __restrict__ deng,
    hf* lds, float* sred)
{
  constexpr int OW  = Wimg - N + 1;
  constexpr int OV  = Himg - N + 1;
  constexpr int CH  = (N >= 9) ? 2 : 3;          // row-chunks
  constexpr int NB  = (OW + 15) / 16;            // 16-col bands
  constexpr int QUO = OV / CH, REM = OV % CH;
  constexpr int OVmax = QUO + (REM ? 1 : 0);
  constexpr int TIL = (OVmax + 15) / 16;         // v-tiles (max)
  constexpr int THT = TIL + 1;                   // h-tiles == staged-row tiles
  constexpr int RH  = THT * 16;                  // LDS rows (<= 80)
  constexpr GaussW<N> GW{};

  const int tid   = threadIdx.x;
  const int band  = b % NB;
  const int rest  = b / NB;
  const int chunk = rest % CH;
  const int bc    = rest / CH;
  const int x0    = band * 16;
  const int r0    = chunk * QUO + (chunk < REM ? chunk : REM);
  const int OVc   = QUO + (chunk < REM ? 1 : 0);
  const int Rc    = OVc + N - 1;                 // valid staged rows
  const int TILc  = (OVc + 15) / 16;

  hf* Ar = lds;
  hf* Ap = lds + AOFF;
  hf* Hh = lds + HOFF;

  // ---- stage r,p rows as fp16 (zero the tail rows: zero-padded Toeplitz
  // taps multiply them — must be finite, NaN*0=NaN would corrupt outputs) ----
  for (int u = tid; u < RH * 16; u += 256) {
    const int row = u >> 4;
    const int s   = u & 15;
    const int arr = s >> 3;
    const int c4  = s & 7;
    hf* dst = (arr ? Ap : Ar) + row * SR + 4 * c4;
    if (row < Rc) {
      int idx = bc * HW + (r0 + row) * Wimg + x0 + 4 * c4;
      if (idx > TOTAL - 4) idx = TOTAL - 4;      // tail clamp; garbage->masked
      fvec4 v = *(const fvec4*)((arr ? xim : recons) + idx);
      *(h4*)dst = (h4){(hf)v[0], (hf)v[1], (hf)v[2], (hf)v[3]};
    } else {
      *(h4*)dst = (h4){(hf)0.f, (hf)0.f, (hf)0.f, (hf)0.f};
    }
  }
  __syncthreads();

  const int lane = tid & 63;
  const int ln   = lane & 15;
  const int quad = lane >> 4;
  const int wave = tid >> 6;
  const f4 zf = {0.f, 0.f, 0.f, 0.f};

  // Toeplitz weight fragment: value w[k - ln], k = quad*8+j. Serves as the
  // B operand of the h-conv (B[k][n=ln]) AND the A operand of the v-conv
  // (A[m=ln][k]). Select-chain keeps constexpr weights out of memory.
  h8 wfrag;
  #pragma unroll
  for (int j = 0; j < 8; ++j) {
    const int k = quad * 8 + j;
    float wv = 0.f;
    #pragma unroll
    for (int d = 0; d < N; ++d) if (k - ln == d) wv = GW.w[d];
    wfrag[j] = (hf)wv;
  }

  // ---- Phase H: horizontal conv via MFMA, one 16-row tile per wave ----
  // A[m=ln][k=quad*8+j] = staged row (t*16+ln), cols quad*8.. (one b128)
  for (int t = wave; t < THT; t += 4) {
    const int ao = (t * 16 + ln) * SR + quad * 8;
    h8 ra = *(const h8*)(Ar + ao);
    h8 pa = *(const h8*)(Ap + ao);
    h8 rsq = ra * ra;
    h8 psq = pa * pa;
    h8 rp  = ra * pa;
    f4 d0 = __builtin_amdgcn_mfma_f32_16x16x32_f16(ra,  wfrag, zf, 0, 0, 0);
    f4 d1 = __builtin_amdgcn_mfma_f32_16x16x32_f16(pa,  wfrag, zf, 0, 0, 0);
    f4 d2 = __builtin_amdgcn_mfma_f32_16x16x32_f16(rsq, wfrag, zf, 0, 0, 0);
    f4 d3 = __builtin_amdgcn_mfma_f32_16x16x32_f16(psq, wfrag, zf, 0, 0, 0);
    f4 d4 = __builtin_amdgcn_mfma_f32_16x16x32_f16(rp,  wfrag, zf, 0, 0, 0);
    #pragma unroll
    for (int reg = 0; reg < 4; ++reg) {
      hf* hb = Hh + (t * 16 + quad * 4 + reg) * SH + ln;  // C/D: row=quad*4+reg, col=ln
      hb[0 * 16] = (hf)d0[reg];
      hb[1 * 16] = (hf)d1[reg];
      hb[2 * 16] = (hf)d2[reg];
      hb[3 * 16] = (hf)d3[reg];
      hb[4 * 16] = (hf)d4[reg];
    }
  }
  __syncthreads();

  // ---- Phase V: vertical conv via MFMA + pointwise on C fragments ----
  float numAcc = 0.f, denAcc = 0.f;
  for (int v = wave; v < TILc; v += 4) {
    const int j0 = v * 16;
    f4 C[5];
    #pragma unroll
    for (int c = 0; c < 5; ++c) {
      const hf* bp = Hh + (j0 + quad * 8) * SH + c * 16 + ln;  // B[k][n=ln]
      h8 bf;
      #pragma unroll
      for (int jj = 0; jj < 8; ++jj) bf[jj] = bp[jj * SH];
      C[c] = __builtin_amdgcn_mfma_f32_16x16x32_f16(wfrag, bf, zf, 0, 0, 0);
    }
    #pragma unroll
    for (int reg = 0; reg < 4; ++reg) {
      const int orow = j0 + quad * 4 + reg;
      const int ocol = x0 + ln;
      if (orow < OVc && ocol < OW) {
        float mu1 = C[0][reg], mu2 = C[1][reg];
        float sGT = fmaxf(C[2][reg] - mu1 * mu1, 0.f);
        float sP  = fmaxf(C[3][reg] - mu2 * mu2, 0.f);
        float sGP = C[4][reg] - mu1 * mu2;
        float g  = __fdividef(sGP, sGT + EPSF);
        float sv = sP - g * sGP;
        if (sGT < EPSF) { g = 0.f; sv = sP; sGT = 0.f; }
        if (sP  < EPSF) { g = 0.f; sv = 0.f; }
        if (g < 0.f)    { sv = sP; g = 0.f; }
        if (sv <= EPSF) sv = EPSF;
        numAcc += __log10f(1.f + __fdividef(g * g * sGT, sv + 2.0f));
        denAcc += __log10f(1.f + sGT * 0.5f);
      }
    }
  }

  // ---- block reduction ----
  #pragma unroll
  for (int off = 32; off > 0; off >>= 1) {
    numAcc += __shfl_down(numAcc, off);
    denAcc += __shfl_down(denAcc, off);
  }
  const int wid = tid >> 6;
  if (lane == 0) { sred[wid] = numAcc; sred[4 + wid] = denAcc; }
  __syncthreads();
  if (tid == 0) {
    atomicAdd(&numg[bc], sred[0] + sred[1] + sred[2] + sred[3]);
    atomicAdd(&deng[bc], sred[4] + sred[5] + sred[6] + sred[7]);
  }
}

__device__ __forceinline__ void dot_body(
    int b, const float* __restrict__ r, const float* __restrict__ x,
    const float* __restrict__ Wl, float* __restrict__ dots, float* sred)
{
  const int img = b >> 3;
  const int ch  = b & 7;
  constexpr int Q = CHW / 4;
  constexpr int per = (Q + 7) / 8;
  const int i0 = ch * per;
  const int i1 = (i0 + per < Q) ? (i0 + per) : Q;
  const int tid = threadIdx.x;
  const fvec4* r4 = (const fvec4*)(r + (size_t)img * CHW);
  const fvec4* x4 = (const fvec4*)(x + (size_t)img * CHW);
  const fvec4* w4 = (const fvec4*)Wl;
  float acc = 0.f;
  for (int i = i0 + tid; i < i1; i += 256) {
    fvec4 rv = r4[i], xv = x4[i], wv = w4[i];
    acc += (xv[0] - rv[0]) * wv[0] + (xv[1] - rv[1]) * wv[1]
         + (xv[2] - rv[2]) * wv[2] + (xv[3] - rv[3]) * wv[3];
  }
  #pragma unroll
  for (int off = 32; off > 0; off >>= 1) acc += __shfl_down(acc, off);
  const int lane = tid & 63, wid = tid >> 6;
  if (lane == 0) sred[wid] = acc;
  __syncthreads();
  if (tid == 0) atomicAdd(&dots[img], sred[0] + sred[1] + sred[2] + sred[3]);
}

// grid: dot first (memory-bound; overlaps compute tail), then scales
constexpr int GD  = Bimg * 8;                 // 1024
constexpr int B17 = 14 * 2 * BCN;             // 10752
constexpr int B9  = 15 * 2 * BCN;             // 11520
constexpr int B5  = 15 * 3 * BCN;             // 17280
constexpr int B3  = 15 * 3 * BCN;             // 17280
constexpr int E17 = GD + B17;
constexpr int E9  = E17 + B9;
constexpr int E5  = E9 + B5;
constexpr int GALL = E5 + B3;

__global__ __launch_bounds__(256, 6) void vif_fat_kernel(
    const float* __restrict__ recons, const float* __restrict__ xim,
    const float* __restrict__ Wl, float* __restrict__ ws)
{
  extern __shared__ hf lds[];
  __shared__ float sred[8];
  float* numg = ws;
  float* deng = ws + 384;
  float* dots = ws + 768;
  const int b = blockIdx.x;
  if      (b < GD)  dot_body(b, recons, xim, Wl, dots, sred);
  else if (b < E17) vif_body<17>(b - GD,  recons, xim, numg, deng, lds, sred);
  else if (b < E9)  vif_body< 9>(b - E17, recons, xim, numg, deng, lds, sred);
  else if (b < E5)  vif_body< 5>(b - E9,  recons, xim, numg, deng, lds, sred);
  else              vif_body< 3>(b - E5,  recons, xim, numg, deng, lds, sred);
}

__global__ __launch_bounds__(128) void finalize_kernel(
    const float* __restrict__ ws, float* __restrict__ out)
{
  __shared__ float s1[128], s2[128];
  const int t = threadIdx.x;
  float d = ws[768 + t];
  float psq = d * d;
  float vimg = 0.f;
  #pragma unroll
  for (int c = 0; c < 3; ++c) {
    int bc = t * 3 + c;
    vimg += ws[bc] / ws[384 + bc];
  }
  float rl = 1.f - vimg * (1.f / 3.f);
  s1[t] = psq; s2[t] = rl;
  __syncthreads();
  for (int off = 64; off > 0; off >>= 1) {
    if (t < off) { s1[t] += s1[t + off]; s2[t] += s2[t + off]; }
    __syncthreads();
  }
  if (t == 0) {
    float pred = s1[0] * (1.f / 128.f);
    float rec  = s2[0] * (1.f / 128.f);
    out[0] = pred + rec;
    out[1] = rec;
    out[2] = pred;
  }
}

extern "C" void kernel_launch(void* const* d_in, const int* in_sizes, int n_in,
                              void* d_out, int out_size, void* d_ws, size_t ws_size,
                              hipStream_t stream) {
  const float* recons = (const float*)d_in[0];
  const float* x      = (const float*)d_in[1];
  const float* Wl     = (const float*)d_in[2];
  float* ws  = (float*)d_ws;
  float* out = (float*)d_out;

  hipMemsetAsync(d_ws, 0, 896 * sizeof(float), stream);

  vif_fat_kernel<<<GALL, 256, LDSB, stream>>>(recons, x, Wl, ws);

  finalize_kernel<<<1, 128, 0, stream>>>(ws, out);
}

// Round 10
// 272.361 us; speedup vs baseline: 1.2874x; 1.2874x over previous
//
#include <hip/hip_runtime.h>

#define Himg 135
#define Wimg 240
#define Bimg 128
#define Cimg 3
#define BCN (Bimg*Cimg)
#define HW (Himg*Wimg)
#define CHW (Cimg*HW)
#define EPSF 1e-10f

typedef float fvec4 __attribute__((ext_vector_type(4)));
typedef _Float16 hf;
typedef hf h8 __attribute__((ext_vector_type(8)));
typedef float f4 __attribute__((ext_vector_type(4)));

// Compile-time exp (double Taylor) for the normalization constant.
constexpr double cexp(double x) {
  double s = 1.0, t = 1.0;
  for (int i = 1; i < 48; ++i) { t *= x / (double)i; s += t; }
  return s;
}
template<int N>
struct GaussW {
  float inv, rsum;
  constexpr GaussW() : inv(0), rsum(0) {
    const float sig = (float)N / 5.0f;
    inv = 1.0f / (2.0f * sig * sig);
    float ssum = 0.f;
    for (int i = 0; i < N; ++i) {
      float d = (float)(i - N / 2);
      ssum += (float)cexp((double)(-(d * d) * inv));
    }
    rsum = 1.0f / ssum;
  }
};

// ws layout (floats): [0,384) num, [384,768) den, [768,896) per-image dots

template<int N>
__device__ __forceinline__ void vif_body(
    int b, const float* __restrict__ recons, const float* __restrict__ xim,
    float* __restrict__ numg, float* __restrict__ deng,
    hf* Ht, float* sred)
{
  constexpr int OW  = Wimg - N + 1;
  constexpr int OV  = Himg - N + 1;
  constexpr int NB  = (OW + 15) / 16;        // 16-col bands
  constexpr int TIL = (OV + 15) / 16;        // v-tiles
  constexpr int THT = TIL + 1;               // h-tiles (k-span = 16*TIL-16+32)
  constexpr int RHP = (THT * 16 <= 144) ? 152 : 168;  // padded row dim:
  // RHP*2 bytes divisible by 16 (b128 alignment); bank stride 5*RHP halves
  // gives <=2-way conflicts (free) for both u16 writes and b128 reads.
  constexpr GaussW<N> GW{};

  const int tid  = threadIdx.x;
  const int band = b % NB;
  const int bc   = b / NB;
  const int x0   = band * 16;
  const int lane = tid & 63;
  const int ln   = lane & 15;
  const int quad = lane >> 4;
  const int wave = tid >> 6;
  const f4 zf = {0.f, 0.f, 0.f, 0.f};

  // Toeplitz weight fragment w[k-ln], k=quad*8+j — shared by h-conv (as B)
  // and v-conv (as A). R9 BUG was here: tap index d in [0,N) maps to grid
  // offset d - N/2 (reference grid is -(N//2)..N//2) — the shift is required.
  h8 wfrag;
  {
    #pragma unroll
    for (int j = 0; j < 8; ++j) {
      const int di = quad * 8 + j - ln;
      const float fd = (float)(di - N / 2);
      float v = __expf(-(fd * fd) * GW.inv) * GW.rsum;
      v = ((unsigned)di < (unsigned)N) ? v : 0.f;
      wfrag[j] = (hf)v;
    }
  }

  const float* rb = recons + bc * HW;
  const float* pb = xim + bc * HW;

  // ---- Phase H: horizontal conv via MFMA, A-fragment straight from global.
  // A[m=ln][k=quad*8+j] = image row (t*16+ln), col x0+quad*8+j. 16x32 tile =
  // 64 lanes x 8 elems, zero redundancy. Rows >= Himg zeroed (keeps H finite
  // for the zero-weight Toeplitz taps; NaN*0 hazard).
  for (int t = wave; t < THT; t += 4) {
    const int row = t * 16 + ln;
    const bool valid = row < Himg;
    int idx = row * Wimg + x0 + quad * 8;
    if (idx > HW - 8) idx = HW - 8;          // in-image clamp (tail tiles)
    fvec4 r0 = *(const fvec4*)(rb + idx);
    fvec4 r1 = *(const fvec4*)(rb + idx + 4);
    fvec4 p0 = *(const fvec4*)(pb + idx);
    fvec4 p1 = *(const fvec4*)(pb + idx + 4);
    h8 ra, pa;
    #pragma unroll
    for (int k = 0; k < 4; ++k) {
      ra[k] = (hf)r0[k]; ra[4 + k] = (hf)r1[k];
      pa[k] = (hf)p0[k]; pa[4 + k] = (hf)p1[k];
    }
    if (!valid) {
      #pragma unroll
      for (int k = 0; k < 8; ++k) { ra[k] = (hf)0.f; pa[k] = (hf)0.f; }
    }
    h8 rsq = ra * ra, psq = pa * pa, rp = ra * pa;
    f4 d0 = __builtin_amdgcn_mfma_f32_16x16x32_f16(ra,  wfrag, zf, 0, 0, 0);
    f4 d1 = __builtin_amdgcn_mfma_f32_16x16x32_f16(pa,  wfrag, zf, 0, 0, 0);
    f4 d2 = __builtin_amdgcn_mfma_f32_16x16x32_f16(rsq, wfrag, zf, 0, 0, 0);
    f4 d3 = __builtin_amdgcn_mfma_f32_16x16x32_f16(psq, wfrag, zf, 0, 0, 0);
    f4 d4 = __builtin_amdgcn_mfma_f32_16x16x32_f16(rp,  wfrag, zf, 0, 0, 0);
    // C/D layout: row = quad*4+reg, col = ln. Store transposed: Ht[col][ch][row]
    #pragma unroll
    for (int reg = 0; reg < 4; ++reg) {
      const int hrow = t * 16 + quad * 4 + reg;
      hf* hb = Ht + (ln * 5) * RHP + hrow;
      hb[0 * RHP] = (hf)d0[reg];
      hb[1 * RHP] = (hf)d1[reg];
      hb[2 * RHP] = (hf)d2[reg];
      hb[3 * RHP] = (hf)d3[reg];
      hb[4 * RHP] = (hf)d4[reg];
    }
  }
  __syncthreads();

  // ---- Phase V: vertical conv via MFMA; B-frag = ONE ds_read_b128/channel.
  // B[k=quad*8+jj][n=ln] = Ht[(ln*5+c)*RHP + j0+quad*8+jj] — contiguous.
  float numAcc = 0.f, denAcc = 0.f;
  for (int v = wave; v < TIL; v += 4) {
    const int j0 = v * 16;
    f4 C[5];
    #pragma unroll
    for (int c = 0; c < 5; ++c) {
      h8 bf = *(const h8*)(Ht + (ln * 5 + c) * RHP + j0 + quad * 8);
      C[c] = __builtin_amdgcn_mfma_f32_16x16x32_f16(wfrag, bf, zf, 0, 0, 0);
    }
    #pragma unroll
    for (int reg = 0; reg < 4; ++reg) {
      const int orow = j0 + quad * 4 + reg;
      const int ocol = x0 + ln;
      if (orow < OV && ocol < OW) {
        float mu1 = C[0][reg], mu2 = C[1][reg];
        float sGT = fmaxf(C[2][reg] - mu1 * mu1, 0.f);
        float sP  = fmaxf(C[3][reg] - mu2 * mu2, 0.f);
        float sGP = C[4][reg] - mu1 * mu2;
        float g  = __fdividef(sGP, sGT + EPSF);
        float sv = sP - g * sGP;
        if (sGT < EPSF) { g = 0.f; sv = sP; sGT = 0.f; }
        if (sP  < EPSF) { g = 0.f; sv = 0.f; }
        if (g < 0.f)    { sv = sP; g = 0.f; }
        if (sv <= EPSF) sv = EPSF;
        numAcc += __log10f(1.f + __fdividef(g * g * sGT, sv + 2.0f));
        denAcc += __log10f(1.f + sGT * 0.5f);
      }
    }
  }

  // ---- block reduction ----
  #pragma unroll
  for (int off = 32; off > 0; off >>= 1) {
    numAcc += __shfl_down(numAcc, off);
    denAcc += __shfl_down(denAcc, off);
  }
  const int wid = tid >> 6;
  if (lane == 0) { sred[wid] = numAcc; sred[4 + wid] = denAcc; }
  __syncthreads();
  if (tid == 0) {
    atomicAdd(&numg[bc], sred[0] + sred[1] + sred[2] + sred[3]);
    atomicAdd(&deng[bc], sred[4] + sred[5] + sred[6] + sred[7]);
  }
}

__device__ __forceinline__ void dot_body(
    int b, const float* __restrict__ r, const float* __restrict__ x,
    const float* __restrict__ Wl, float* __restrict__ dots, float* sred)
{
  const int img = b >> 3;
  const int ch  = b & 7;
  constexpr int Q = CHW / 4;
  constexpr int per = (Q + 7) / 8;
  const int i0 = ch * per;
  const int i1 = (i0 + per < Q) ? (i0 + per) : Q;
  const int tid = threadIdx.x;
  const fvec4* r4 = (const fvec4*)(r + (size_t)img * CHW);
  const fvec4* x4 = (const fvec4*)(x + (size_t)img * CHW);
  const fvec4* w4 = (const fvec4*)Wl;
  float acc = 0.f;
  for (int i = i0 + tid; i < i1; i += 256) {
    fvec4 rv = r4[i], xv = x4[i], wv = w4[i];
    acc += (xv[0] - rv[0]) * wv[0] + (xv[1] - rv[1]) * wv[1]
         + (xv[2] - rv[2]) * wv[2] + (xv[3] - rv[3]) * wv[3];
  }
  #pragma unroll
  for (int off = 32; off > 0; off >>= 1) acc += __shfl_down(acc, off);
  const int lane = tid & 63, wid = tid >> 6;
  if (lane == 0) sred[wid] = acc;
  __syncthreads();
  if (tid == 0) atomicAdd(&dots[img], sred[0] + sred[1] + sred[2] + sred[3]);
}

// grid: dot first (memory-bound, overlaps), then the 4 scales
constexpr int GD   = Bimg * 8;               // 1024
constexpr int B17  = 14 * BCN;               // 5376
constexpr int B9   = 15 * BCN;               // 5760
constexpr int E17  = GD + B17;
constexpr int E9   = E17 + B9;
constexpr int E5   = E9 + B9;
constexpr int GALL = E5 + B9;                // 23680
constexpr int LDSB = 16 * 5 * 168 * 2;       // Ht max: 26880 B -> 5 blocks/CU

__global__ __launch_bounds__(256, 5) void vif_fat_kernel(
    const float* __restrict__ recons, const float* __restrict__ xim,
    const float* __restrict__ Wl, float* __restrict__ ws)
{
  extern __shared__ hf lds[];
  __shared__ float sred[8];
  float* numg = ws;
  float* deng = ws + 384;
  float* dots = ws + 768;
  const int b = blockIdx.x;
  if      (b < GD)  dot_body(b, recons, xim, Wl, dots, sred);
  else if (b < E17) vif_body<17>(b - GD,  recons, xim, numg, deng, lds, sred);
  else if (b < E9)  vif_body< 9>(b - E17, recons, xim, numg, deng, lds, sred);
  else if (b < E5)  vif_body< 5>(b - E9,  recons, xim, numg, deng, lds, sred);
  else              vif_body< 3>(b - E5,  recons, xim, numg, deng, lds, sred);
}

__global__ __launch_bounds__(128) void finalize_kernel(
    const float* __restrict__ ws, float* __restrict__ out)
{
  __shared__ float s1[128], s2[128];
  const int t = threadIdx.x;
  float d = ws[768 + t];
  float psq = d * d;
  float vimg = 0.f;
  #pragma unroll
  for (int c = 0; c < 3; ++c) {
    int bc = t * 3 + c;
    vimg += ws[bc] / ws[384 + bc];
  }
  float rl = 1.f - vimg * (1.f / 3.f);
  s1[t] = psq; s2[t] = rl;
  __syncthreads();
  for (int off = 64; off > 0; off >>= 1) {
    if (t < off) { s1[t] += s1[t + off]; s2[t] += s2[t + off]; }
    __syncthreads();
  }
  if (t == 0) {
    float pred = s1[0] * (1.f / 128.f);
    float rec  = s2[0] * (1.f / 128.f);
    out[0] = pred + rec;
    out[1] = rec;
    out[2] = pred;
  }
}

extern "C" void kernel_launch(void* const* d_in, const int* in_sizes, int n_in,
                              void* d_out, int out_size, void* d_ws, size_t ws_size,
                              hipStream_t stream) {
  const float* recons = (const float*)d_in[0];
  const float* x      = (const float*)d_in[1];
  const float* Wl     = (const float*)d_in[2];
  float* ws  = (float*)d_ws;
  float* out = (float*)d_out;

  hipMemsetAsync(d_ws, 0, 896 * sizeof(float), stream);

  vif_fat_kernel<<<GALL, 256, LDSB, stream>>>(recons, x, Wl, ws);

  finalize_kernel<<<1, 128, 0, stream>>>(ws, out);
}